// Round 1
// baseline (45.780 us; speedup 1.0000x reference)
//
#include <hip/hip_runtime.h>
#include <hip/hip_bf16.h>

// Elementwise cos over 262144 x 128 float32 (33,554,432 elements).
// Memory-bound: 268 MB total traffic -> ~43 us at 6.3 TB/s.
// float4 vectorized grid-stride loop; __cosf (v_cos_f32) is plenty accurate
// for the 2e-2 threshold with N(0,1) inputs.

__global__ void cos_kernel_f4(const float4* __restrict__ in,
                              float4* __restrict__ out,
                              int n4) {
    int idx = blockIdx.x * blockDim.x + threadIdx.x;
    int stride = gridDim.x * blockDim.x;
    for (int i = idx; i < n4; i += stride) {
        float4 v = in[i];
        float4 r;
        r.x = __cosf(v.x);
        r.y = __cosf(v.y);
        r.z = __cosf(v.z);
        r.w = __cosf(v.w);
        out[i] = r;
    }
}

extern "C" void kernel_launch(void* const* d_in, const int* in_sizes, int n_in,
                              void* d_out, int out_size, void* d_ws, size_t ws_size,
                              hipStream_t stream) {
    const float* in = (const float*)d_in[0];
    float* out = (float*)d_out;

    int n = out_size;            // 33,554,432, divisible by 4
    int n4 = n / 4;              // 8,388,608 float4s

    const int block = 256;
    int grid = (n4 + block - 1) / block;
    if (grid > 2048) grid = 2048;   // grid-stride; ~8 blocks/CU

    cos_kernel_f4<<<grid, block, 0, stream>>>(
        (const float4*)in, (float4*)out, n4);
}